// Round 6
// baseline (1914.319 us; speedup 1.0000x reference)
//
#include <hip/hip_runtime.h>

#define NN   25000
#define EE   400000
#define FIN  256
#define CC   32
#define AA   9
#define WN   288   // CC*AA
#define BB   8
#define HH   64
#define SS   4
#define FOUT 256
#define MAXSEG 8   // LDS segment slots per 64-edge block; overflow -> global atomics

__device__ __forceinline__ float silu_f(float v){ return v / (1.0f + __expf(-v)); }
__device__ __forceinline__ float bfu(unsigned int u){  // low 16 bits = bf16
  union{unsigned int i; float f;} v; v.i = u << 16; return v.f;
}
__device__ __forceinline__ unsigned short f2bf(float f){  // RNE
  union{float f; unsigned int i;} v; v.f = f;
  unsigned int u = v.i;
  u += 0x7fffu + ((u >> 16) & 1u);
  return (unsigned short)(u >> 16);
}

// ---------------- h = bf16((x @ W1) * 0.25) : [N, 32] ----------------
__global__ __launch_bounds__(256) void k_h(const float* __restrict__ x,
                                           const float* __restrict__ W1,
                                           unsigned short* __restrict__ hb){
  int gid = blockIdx.x * 256 + threadIdx.x;   // N*CC threads exactly
  int n = gid >> 5, c = gid & 31;
  const float* xr = x + (size_t)n * FIN;
  float acc = 0.f;
  #pragma unroll 8
  for (int f = 0; f < FIN; ++f) acc = fmaf(xr[f], W1[f * CC + c], acc);
  hb[gid] = f2bf(acc * 0.25f);
}

// ---------------- CSR build: histogram / scan / scatter ----------------
__global__ __launch_bounds__(256) void k_hist(const int* __restrict__ eidx,
                                              int* __restrict__ counts){
  int e = blockIdx.x * 256 + threadIdx.x;
  if (e < EE) atomicAdd(&counts[eidx[e]], 1);
}

__global__ __launch_bounds__(1024) void k_scan(const int* __restrict__ counts,
                                               int* __restrict__ offsets){
  __shared__ int s[1024];
  const int tid = threadIdx.x;
  const int i0 = tid * 25;           // 1024*25 = 25600 >= NN
  int tot = 0;
  for (int i = 0; i < 25; ++i){ int idx = i0 + i; if (idx < NN) tot += counts[idx]; }
  s[tid] = tot;
  __syncthreads();
  for (int off = 1; off < 1024; off <<= 1){
    int v = s[tid];
    int add = (tid >= off) ? s[tid - off] : 0;
    __syncthreads();
    s[tid] = v + add;
    __syncthreads();
  }
  int run = s[tid] - tot;
  for (int i = 0; i < 25; ++i){
    int idx = i0 + i;
    if (idx < NN){ offsets[idx] = run; run += counts[idx]; }
  }
}

__global__ __launch_bounds__(256) void k_scatter(const int* __restrict__ eidx,
                                                 const int* __restrict__ offsets,
                                                 int* __restrict__ cursor,
                                                 int* __restrict__ eperm){
  int e = blockIdx.x * 256 + threadIdx.x;
  if (e < EE){
    int d = eidx[e];
    int p = offsets[d] + atomicAdd(&cursor[d], 1);
    eperm[p] = e;
  }
}

// ---------------- permute/pack: gather into dst-sorted SoA bf16 streams ----------------
// Pure gather, no LDS/barriers — absorbs the random-access latency with TLP.
__global__ __launch_bounds__(256) void k_perm(const int* __restrict__ eperm,
                                              const float* __restrict__ eemb,
                                              const float* __restrict__ sh,
                                              const int* __restrict__ eidx,
                                              unsigned short* __restrict__ eembp, // [8][E]
                                              unsigned short* __restrict__ shp,   // [9][E]
                                              int* __restrict__ srcp,
                                              int* __restrict__ dstp){
  int p = blockIdx.x * 256 + threadIdx.x;
  if (p >= EE) return;
  int e = eperm[p];
  float4 a0 = *(const float4*)&eemb[(size_t)e * 8];
  float4 a1 = *(const float4*)&eemb[(size_t)e * 8 + 4];
  eembp[0 * EE + p] = f2bf(a0.x);
  eembp[1 * EE + p] = f2bf(a0.y);
  eembp[2 * EE + p] = f2bf(a0.z);
  eembp[3 * EE + p] = f2bf(a0.w);
  eembp[4 * EE + p] = f2bf(a1.x);
  eembp[5 * EE + p] = f2bf(a1.y);
  eembp[6 * EE + p] = f2bf(a1.z);
  eembp[7 * EE + p] = f2bf(a1.w);
  #pragma unroll
  for (int a = 0; a < 9; ++a)
    shp[a * EE + p] = f2bf(sh[(size_t)e * 9 + a]);
  srcp[p] = eidx[EE + e];
  dstp[p] = eidx[e];
}

// ---------------- fused edge MLP + TP + segmented reduction (64 edges/block) ----------------
// LDS ~61 KB < 64 KiB. All vector-accessed LDS arrays are force-aligned to 16 B:
// ds_read/write_b128 faults on <16B alignment, and ushort arrays default to align 2.
__global__ __launch_bounds__(256) void k_edge(
    const unsigned short* __restrict__ eembp, // [8][E] bf16, dst-sorted
    const unsigned short* __restrict__ shp,   // [9][E] bf16
    const int* __restrict__ srcp,             // [E]
    const int* __restrict__ dstp,             // [E]
    const unsigned short* __restrict__ hb,    // [N][32] bf16
    const float* __restrict__ Wm1,            // [8][64]
    const float* __restrict__ Wm2,            // [64][64]
    const float* __restrict__ Wm3,            // [64][288]
    float* __restrict__ agg){
  __shared__ float ee_s[8][64];      // [b][e]
  __shared__ float sh_s[9][64];      // [a][e]
  __shared__ float hs_s[64][33];     // [e][c]
  __shared__ float wm1_s[8][64];
  __shared__ __align__(16) unsigned short wm2_s[64][66];
  __shared__ __align__(16) unsigned short t1_s[64][72];   // [j][e] bf16, row 144 B
  __shared__ __align__(16) unsigned short t2_s[64][72];   // [j][e] bf16
  __shared__ float w3_s[8 * WN];            // 8-row chunk of Wm3
  __shared__ float acc2_s[MAXSEG][WN];
  __shared__ int src_s[64], dst_s[64], seg_s[64], dlist_s[MAXSEG];
  __shared__ int nseg_s;
  const int tid = threadIdx.x;
  const int e0 = blockIdx.x * 64;

  // zero segment accumulators (MAXSEG*WN = 2304 = 9*256)
  #pragma unroll
  for (int t = 0; t < 9; ++t) ((float*)acc2_s)[t * 256 + tid] = 0.f;

  if (tid < 64){
    src_s[tid] = srcp[e0 + tid];
    dst_s[tid] = dstp[e0 + tid];
  }
  // stage ee: stream s=tid>>5 (8 streams), 2 edges per lane
  {
    int s = tid >> 5, l = tid & 31;
    const unsigned int w = *(const unsigned int*)&eembp[(size_t)s * EE + e0 + 2 * l];
    ee_s[s][2 * l]     = bfu(w & 0xffffu);
    ee_s[s][2 * l + 1] = bfu(w >> 16);
  }
  // stage sh: 9 streams
  for (int idx = tid; idx < 9 * 32; idx += 256){
    int s = idx >> 5, l = idx & 31;
    const unsigned int w = *(const unsigned int*)&shp[(size_t)s * EE + e0 + 2 * l];
    sh_s[s][2 * l]     = bfu(w & 0xffffu);
    sh_s[s][2 * l + 1] = bfu(w >> 16);
  }
  // stage Wm1 (512 floats) and Wm2 (4096 -> bf16)
  #pragma unroll
  for (int t = 0; t < 2; ++t){
    int idx = t * 256 + tid;
    ((float*)wm1_s)[idx] = Wm1[idx];
  }
  #pragma unroll
  for (int t = 0; t < 16; ++t){
    int idx = t * 256 + tid;
    wm2_s[idx >> 6][idx & 63] = f2bf(Wm2[idx]);
  }
  __syncthreads();

  // segment detection: serial on thread 0 (R3-proven; ~64 LDS reads, negligible)
  if (tid == 0){
    int ns = 0;
    for (int e = 0; e < 64; ++e){
      if (e == 0 || dst_s[e] != dst_s[e - 1]){
        if (ns < MAXSEG) dlist_s[ns] = dst_s[e];
        ++ns;
      }
      seg_s[e] = ns - 1;
    }
    nseg_s = ns;
  }
  // stage h rows (needs src_s): thread -> (edge, quarter-row)
  {
    int e = tid >> 2, q = tid & 3;
    uint4 r = *(const uint4*)&hb[(size_t)src_s[e] * CC + q * 8];
    float* dst = &hs_s[e][q * 8];
    dst[0] = bfu(r.x & 0xffffu); dst[1] = bfu(r.x >> 16);
    dst[2] = bfu(r.y & 0xffffu); dst[3] = bfu(r.y >> 16);
    dst[4] = bfu(r.z & 0xffffu); dst[5] = bfu(r.z >> 16);
    dst[6] = bfu(r.w & 0xffffu); dst[7] = bfu(r.w >> 16);
  }
  __syncthreads();

  const int j  = tid & 63;
  const int eg = tid >> 6;    // 4 groups of 16 edges

  // ---- layer 1: t1[j][e] = silu(sum_b ee[b][e] * Wm1[b][j]) ----
  {
    float acc[16] = {};
    #pragma unroll
    for (int b = 0; b < 8; ++b){
      float wv = wm1_s[b][j];
      #pragma unroll
      for (int k = 0; k < 16; ++k)
        acc[k] = fmaf(ee_s[b][eg * 16 + k], wv, acc[k]);
    }
    union { unsigned short us[8]; uint4 v; } p0, p1;
    #pragma unroll
    for (int k = 0; k < 8; ++k) p0.us[k] = f2bf(silu_f(acc[k]));
    #pragma unroll
    for (int k = 0; k < 8; ++k) p1.us[k] = f2bf(silu_f(acc[8 + k]));
    *(uint4*)&t1_s[j][eg * 16]     = p0.v;
    *(uint4*)&t1_s[j][eg * 16 + 8] = p1.v;
  }
  __syncthreads();

  // ---- layer 2: t2[j][e] = silu(sum_h t1[h][e] * Wm2[h][j]) ----
  {
    float acc[16] = {};
    for (int hh = 0; hh < 64; ++hh){
      float wv = bfu((unsigned int)wm2_s[hh][j]);
      uint4 ra = *(const uint4*)&t1_s[hh][eg * 16];
      uint4 rb = *(const uint4*)&t1_s[hh][eg * 16 + 8];
      float a[16];
      a[0]=bfu(ra.x&0xffffu); a[1]=bfu(ra.x>>16); a[2]=bfu(ra.y&0xffffu); a[3]=bfu(ra.y>>16);
      a[4]=bfu(ra.z&0xffffu); a[5]=bfu(ra.z>>16); a[6]=bfu(ra.w&0xffffu); a[7]=bfu(ra.w>>16);
      a[8]=bfu(rb.x&0xffffu); a[9]=bfu(rb.x>>16); a[10]=bfu(rb.y&0xffffu); a[11]=bfu(rb.y>>16);
      a[12]=bfu(rb.z&0xffffu); a[13]=bfu(rb.z>>16); a[14]=bfu(rb.w&0xffffu); a[15]=bfu(rb.w>>16);
      #pragma unroll
      for (int k = 0; k < 16; ++k) acc[k] = fmaf(a[k], wv, acc[k]);
    }
    union { unsigned short us[8]; uint4 v; } p0, p1;
    #pragma unroll
    for (int k = 0; k < 8; ++k) p0.us[k] = f2bf(silu_f(acc[k]));
    #pragma unroll
    for (int k = 0; k < 8; ++k) p1.us[k] = f2bf(silu_f(acc[8 + k]));
    *(uint4*)&t2_s[j][eg * 16]     = p0.v;
    *(uint4*)&t2_s[j][eg * 16 + 8] = p1.v;
  }

  // ---- layer 3 + TP + segmented scatter (8 chunks of 8 Wm3 rows) ----
  {
    const int tj = tid & 31, te = tid >> 5;   // 8 edges per thread: e = te*8 + i
    int cm[9], am[9];
    #pragma unroll
    for (int m = 0; m < 9; ++m){
      int jj = tj + 32 * m;
      cm[m] = jj / 9;
      am[m] = jj - 9 * cm[m];
    }
    float acc[8][9] = {};
    for (int hc = 0; hc < 8; ++hc){
      __syncthreads();   // hc=0: covers t2 writes; others: w3 reuse
      #pragma unroll
      for (int t = 0; t < 9; ++t){
        int idx = t * 256 + tid;
        w3_s[idx] = Wm3[(size_t)(hc * 8) * WN + idx];
      }
      __syncthreads();
      #pragma unroll
      for (int hh = 0; hh < 8; ++hh){
        uint4 r = *(const uint4*)&t2_s[hc * 8 + hh][te * 8];
        float a[8];
        a[0]=bfu(r.x&0xffffu); a[1]=bfu(r.x>>16); a[2]=bfu(r.y&0xffffu); a[3]=bfu(r.y>>16);
        a[4]=bfu(r.z&0xffffu); a[5]=bfu(r.z>>16); a[6]=bfu(r.w&0xffffu); a[7]=bfu(r.w>>16);
        #pragma unroll
        for (int m = 0; m < 9; ++m){
          float wv = w3_s[hh * WN + tj + 32 * m];
          #pragma unroll
          for (int i = 0; i < 8; ++i) acc[i][m] = fmaf(a[i], wv, acc[i][m]);
        }
      }
    }
    #pragma unroll
    for (int i = 0; i < 8; ++i){
      int e = te * 8 + i;
      int sg = seg_s[e];
      if (sg < MAXSEG){
        #pragma unroll
        for (int m = 0; m < 9; ++m){
          float msg = acc[i][m] * hs_s[e][cm[m]] * sh_s[am[m]][e];
          atomicAdd(&acc2_s[sg][tj + 32 * m], msg);
        }
      } else {
        int d = dst_s[e];
        #pragma unroll
        for (int m = 0; m < 9; ++m){
          float msg = acc[i][m] * hs_s[e][cm[m]] * sh_s[am[m]][e];
          atomicAdd(&agg[(size_t)d * WN + tj + 32 * m], msg);
        }
      }
    }
  }
  __syncthreads();
  // epilogue: one atomic row per segment
  int ns = nseg_s; if (ns > MAXSEG) ns = MAXSEG;
  for (int s = 0; s < ns; ++s){
    int d = dlist_s[s];
    for (int jj = tid; jj < WN; jj += 256)
      atomicAdd(&agg[(size_t)d * WN + jj], acc2_s[s][jj]);
  }
}

// ---------------- sc_out = (x ⊗ node_attrs) @ Wsc : [N, 256] ----------------
__global__ __launch_bounds__(256) void k_sc(const float* __restrict__ x,
                                            const float* __restrict__ na,
                                            const float* __restrict__ Wsc,
                                            float* __restrict__ out){
  __shared__ __align__(16) float As[32][64];
  __shared__ __align__(16) float Bs[32][64];
  const int row0 = blockIdx.x * 64;
  const int col0 = blockIdx.y * 64;
  const int tid = threadIdx.x;
  const int tm = tid >> 4, tn = tid & 15;
  float acc[4][4] = {};
  for (int kc = 0; kc < FIN * SS; kc += 32){
    #pragma unroll
    for (int t = 0; t < 8; ++t){
      int idx = tid + t * 256;
      int m = idx & 63, kk = idx >> 6;
      int n = row0 + m;
      int k = kc + kk;
      float v = 0.f;
      if (n < NN) v = x[(size_t)n * FIN + (k >> 2)] * na[n * SS + (k & 3)];
      As[kk][m] = v;
    }
    #pragma unroll
    for (int t = 0; t < 8; ++t){
      int idx = tid + t * 256;
      int o = idx & 63, kk = idx >> 6;
      Bs[kk][o] = Wsc[(size_t)(kc + kk) * FOUT + col0 + o];
    }
    __syncthreads();
    #pragma unroll
    for (int kk = 0; kk < 32; ++kk){
      float4 av = *(const float4*)&As[kk][tm * 4];
      float4 bv = *(const float4*)&Bs[kk][tn * 4];
      float a[4] = {av.x, av.y, av.z, av.w};
      float b[4] = {bv.x, bv.y, bv.z, bv.w};
      #pragma unroll
      for (int i = 0; i < 4; ++i)
        #pragma unroll
        for (int jj = 0; jj < 4; ++jj)
          acc[i][jj] = fmaf(a[i], b[jj], acc[i][jj]);
    }
    __syncthreads();
  }
  #pragma unroll
  for (int i = 0; i < 4; ++i){
    int n = row0 + tm * 4 + i;
    if (n < NN){
      float4 v = {acc[i][0], acc[i][1], acc[i][2], acc[i][3]};
      *(float4*)&out[(size_t)n * FOUT + col0 + tn * 4] = v;
    }
  }
}

// ---------------- out = silu(agg @ W2) + sc_out ----------------
__global__ __launch_bounds__(256) void k_out(const float* __restrict__ agg,
                                             const float* __restrict__ W2,
                                             float* __restrict__ out){
  __shared__ __align__(16) float As[32][64];
  __shared__ __align__(16) float Bs[32][64];
  const int row0 = blockIdx.x * 64;
  const int col0 = blockIdx.y * 64;
  const int tid = threadIdx.x;
  const int tm = tid >> 4, tn = tid & 15;
  float acc[4][4] = {};
  for (int kc = 0; kc < WN; kc += 32){
    #pragma unroll
    for (int t = 0; t < 8; ++t){
      int idx = tid + t * 256;
      int m = idx & 63, kk = idx >> 6;
      int n = row0 + m;
      float v = 0.f;
      if (n < NN) v = agg[(size_t)n * WN + kc + kk];
      As[kk][m] = v;
    }
    #pragma unroll
    for (int t = 0; t < 8; ++t){
      int idx = tid + t * 256;
      int o = idx & 63, kk = idx >> 6;
      Bs[kk][o] = W2[(size_t)(kc + kk) * FOUT + col0 + o];
    }
    __syncthreads();
    #pragma unroll
    for (int kk = 0; kk < 32; ++kk){
      float4 av = *(const float4*)&As[kk][tm * 4];
      float4 bv = *(const float4*)&Bs[kk][tn * 4];
      float a[4] = {av.x, av.y, av.z, av.w};
      float b[4] = {bv.x, bv.y, bv.z, bv.w};
      #pragma unroll
      for (int i = 0; i < 4; ++i)
        #pragma unroll
        for (int jj = 0; jj < 4; ++jj)
          acc[i][jj] = fmaf(a[i], b[jj], acc[i][jj]);
    }
    __syncthreads();
  }
  #pragma unroll
  for (int i = 0; i < 4; ++i){
    int n = row0 + tm * 4 + i;
    if (n < NN){
      float4 sc = *(const float4*)&out[(size_t)n * FOUT + col0 + tn * 4];
      float4 v;
      v.x = silu_f(acc[i][0]) + sc.x;
      v.y = silu_f(acc[i][1]) + sc.y;
      v.z = silu_f(acc[i][2]) + sc.z;
      v.w = silu_f(acc[i][3]) + sc.w;
      *(float4*)&out[(size_t)n * FOUT + col0 + tn * 4] = v;
    }
  }
}

extern "C" void kernel_launch(void* const* d_in, const int* in_sizes, int n_in,
                              void* d_out, int out_size, void* d_ws, size_t ws_size,
                              hipStream_t stream){
  const float* x    = (const float*)d_in[0];
  const float* na   = (const float*)d_in[1];
  const float* eemb = (const float*)d_in[2];
  const float* shp_in = (const float*)d_in[3];
  const int*   eidx = (const int*)d_in[4];
  const float* W1   = (const float*)d_in[5];
  const float* Wm1  = (const float*)d_in[6];
  const float* Wm2  = (const float*)d_in[7];
  const float* Wm3  = (const float*)d_in[8];
  const float* W2   = (const float*)d_in[9];
  const float* Wsc  = (const float*)d_in[10];
  float* out  = (float*)d_out;

  // ws: agg fp32 [N,288] (28.8 MB) + hb bf16 [N,32] (1.6 MB) = 30.4 MB (<= 32.0 proven)
  float* agg = (float*)d_ws;
  unsigned short* hb = (unsigned short*)((char*)d_ws + (size_t)NN * WN * 4);

  // d_out as pre-k_sc scratch (18.6 MB <= 25.6 MB), fully consumed before k_sc
  int* offsets = (int*)d_out;                    // NN
  int* cursor  = offsets + NN;                   // NN
  int* eperm   = cursor + NN;                    // EE
  int* srcp    = eperm + EE;                     // EE
  int* dstp    = srcp + EE;                      // EE
  unsigned short* eembp = (unsigned short*)(dstp + EE);  // 8*EE bf16
  unsigned short* shp   = eembp + (size_t)8 * EE;        // 9*EE bf16

  hipMemsetAsync(agg, 0, (size_t)NN * WN * sizeof(float), stream);
  hipMemsetAsync(cursor, 0, (size_t)NN * sizeof(int), stream);

  k_h   <<<dim3(NN * CC / 256), dim3(256), 0, stream>>>(x, W1, hb);
  k_hist<<<dim3((EE + 255) / 256), dim3(256), 0, stream>>>(eidx, cursor);
  k_scan<<<dim3(1), dim3(1024), 0, stream>>>(cursor, offsets);
  hipMemsetAsync(cursor, 0, (size_t)NN * sizeof(int), stream);
  k_scatter<<<dim3((EE + 255) / 256), dim3(256), 0, stream>>>(eidx, offsets, cursor, eperm);
  k_perm<<<dim3((EE + 255) / 256), dim3(256), 0, stream>>>(eperm, eemb, shp_in, eidx,
                                                           eembp, shp, srcp, dstp);
  k_edge<<<dim3(EE / 64), dim3(256), 0, stream>>>(eembp, shp, srcp, dstp, hb,
                                                  Wm1, Wm2, Wm3, agg);
  k_sc <<<dim3((NN + 63) / 64, FOUT / 64), dim3(256), 0, stream>>>(x, na, Wsc, out);
  k_out<<<dim3((NN + 63) / 64, FOUT / 64), dim3(256), 0, stream>>>(agg, W2, out);
}